// Round 10
// baseline (562.328 us; speedup 1.0000x reference)
//
#include <hip/hip_runtime.h>

#define N_NODES 50000
#define N_EDGES 800000
#define N_GRAPHS 256
#define F 100  // hidden dim

#define SCAN_B 512
#define SCAN_NB 98          // 98*512 = 50176 >= 50001
#define SCAN_PAD (SCAN_NB * SCAN_B)

#define PART_SZ 6250        // 8 dst partitions * 6250 = 50000
#define FILL_CHUNK 2048

#define NBH 112             // feature half-tile (224-row padded weights, 2 halves)

typedef __attribute__((ext_vector_type(8))) short bf16x8;
typedef __attribute__((ext_vector_type(4))) float f32x4;
typedef unsigned short ushort_t;
typedef unsigned int uint_t;

__device__ inline ushort_t f2bf(float f) {  // RNE float->bf16
  uint_t u = __float_as_uint(f);
  uint_t r = (u + 0x7fffu + ((u >> 16) & 1u)) >> 16;
  return (ushort_t)r;
}
__device__ inline float bflo(uint_t u) { return __uint_as_float(u << 16); }
__device__ inline float bfhi(uint_t u) { return __uint_as_float(u & 0xffff0000u); }

// ---------------- CSR build (counting sort by dst, rebuilt every call) ----------------
// hist/fill dst-range partitioned by blockIdx&7 (XCD round-robin heuristic) so csr/cursor
// atomics+scatters for a dst range stay in one XCD's L2 (R4->R6: fill 55 -> ~20 us).

__global__ __launch_bounds__(256) void hist_kernel(const int* __restrict__ dst,
                                                   int* __restrict__ cnt, int E) {
  int part = blockIdx.x & 7;
  int lo = part * PART_SZ, hi = lo + PART_SZ;
  int base = (blockIdx.x >> 3) * FILL_CHUNK;
  int end = base + FILL_CHUNK; if (end > E) end = E;
  for (int i = base + threadIdx.x; i < end; i += 256) {
    int d = dst[i];
    if (d >= lo && d < hi) atomicAdd(&cnt[d], 1);
  }
}

__global__ __launch_bounds__(SCAN_B) void scan1_kernel(const int* __restrict__ cnt,
                                                       int* __restrict__ excl,
                                                       int* __restrict__ bsum) {
  __shared__ int sh[SCAN_B];
  int t = threadIdx.x;
  int i = blockIdx.x * SCAN_B + t;
  int v = cnt[i];
  sh[t] = v;
  __syncthreads();
  for (int off = 1; off < SCAN_B; off <<= 1) {
    int u = (t >= off) ? sh[t - off] : 0;
    __syncthreads();
    sh[t] += u;
    __syncthreads();
  }
  excl[i] = sh[t] - v;
  if (t == SCAN_B - 1) bsum[blockIdx.x] = sh[t];
}

__global__ __launch_bounds__(128) void scan2_kernel(int* __restrict__ bsum) {
  __shared__ int sh[128];
  int t = threadIdx.x;
  int v = (t < SCAN_NB) ? bsum[t] : 0;
  sh[t] = v;
  __syncthreads();
  for (int off = 1; off < 128; off <<= 1) {
    int u = (t >= off) ? sh[t - off] : 0;
    __syncthreads();
    sh[t] += u;
    __syncthreads();
  }
  if (t < SCAN_NB) bsum[t] = sh[t] - v;
}

__global__ __launch_bounds__(SCAN_B) void scan3_kernel(const int* __restrict__ excl,
                                                       const int* __restrict__ bsum,
                                                       int* __restrict__ offs,
                                                       int* __restrict__ cursor) {
  int i = blockIdx.x * SCAN_B + threadIdx.x;
  int v = excl[i] + bsum[blockIdx.x];
  if (i <= N_NODES) { offs[i] = v; cursor[i] = v; }
}

__global__ __launch_bounds__(256) void fill_kernel(const int* __restrict__ src,
                                                   const int* __restrict__ dst,
                                                   int* __restrict__ cursor,
                                                   int* __restrict__ csr_src, int E) {
  int part = blockIdx.x & 7;
  int lo = part * PART_SZ, hi = lo + PART_SZ;
  int base = (blockIdx.x >> 3) * FILL_CHUNK;
  int end = base + FILL_CHUNK; if (end > E) end = E;
  for (int i = base + threadIdx.x; i < end; i += 256) {
    int d = dst[i];
    if (d >= lo && d < hi) {
      int p = atomicAdd(&cursor[d], 1);
      csr_src[p] = src[i];
    }
  }
}

// ---------------- weight packing: [224][Kp] bf16, zero-padded (rows 200..223, k>=K zero) -------

__global__ void pack_w1_kernel(const float* __restrict__ w1_rel, const float* __restrict__ w1_root,
                               ushort_t* __restrict__ Wp1) {
  int row = blockIdx.x;  // 224
  for (int k = threadIdx.x; k < 352; k += 128) {
    float v = 0.f;
    if (k < 336) {
      if (row < 100) v = w1_rel[row * 336 + k];
      else if (row < 200) v = w1_root[(row - 100) * 336 + k];
    }
    Wp1[(size_t)row * 352 + k] = f2bf(v);
  }
}

__global__ void pack_w_kernel(const float* __restrict__ w_rel, const float* __restrict__ w_root,
                              ushort_t* __restrict__ Wp) {
  int row = blockIdx.x;  // 224
  int l = blockIdx.y;    // 4
  int k = threadIdx.x;   // 128
  float v = 0.f;
  if (k < 100) {
    if (row < 100) v = w_rel[((size_t)l * 100 + row) * 100 + k];
    else if (row < 200) v = w_root[((size_t)l * 100 + row - 100) * 100 + k];
  }
  Wp[((size_t)l * 224 + row) * 128 + k] = f2bf(v);
}

// ---------------- MFMA conv: Zrel = A@Wrel.T (bf16), Zroot = A@Wroot.T + b ----------------
// R10: NO LDS, NO BARRIERS. R6-R9 proved conv is bound by the sum of staging-pipe
// instruction floors (global->VGPR->LDS->VGPR + 2 barriers/chunk), invariant to K-loop
// structure. Each wave's 16 A-rows are private -> the MFMA A-fragment
// (A[m=lane&15][k=q*8+j]) is a direct 16B global load, perfectly coalesced
// (16 rows x 64B contiguous per instruction). B (weights, <=77KB) is wave-shared ->
// L1/L2-resident after first touch; direct per-lane B-fragment loads. ~60-90 VGPR,
// no LDS -> high occupancy; compiler pipelines with fine-grained vmcnt (no barrier drain).
// Zrel/Zroot padded to 128 cols; pad cols never written (poison ~ -3e-13 bf16,
// annihilated downstream by relu + zero weight-pad columns).

template <bool AF32, int NS>
__global__ __launch_bounds__(256) void conv_mfma(
    const void* __restrict__ Aptr, const ushort_t* __restrict__ Wp,
    const float* __restrict__ bias,
    ushort_t* __restrict__ Zrel, ushort_t* __restrict__ Zroot, int Kp) {
  int tid = threadIdx.x;
  int w = tid >> 6, lane = tid & 63, q = lane >> 4, m16 = lane & 15;
  int n0 = blockIdx.x * 64;
  int h = blockIdx.y;  // feature half: weight rows [h*NBH, h*NBH+NBH)
  int arow = n0 + w * 16 + m16;
  int arow_c = arow < N_NODES ? arow : N_NODES - 1;  // clamp load address only

  f32x4 acc[7];
#pragma unroll
  for (int b = 0; b < 7; ++b) acc[b] = (f32x4)0.f;

  const ushort_t* wbase = Wp + (size_t)(h * NBH) * Kp;

#pragma unroll
  for (int s = 0; s < NS; ++s) {
    int base = s * 32 + q * 8;
    bf16x8 a;
    if (AF32) {
      bf16x8 val = (bf16x8)0;
      if (base < 336) {  // 336 % 8 == 0: no partial straddle; base<336 => base+7<336
        const float* p = (const float*)Aptr + (size_t)arow_c * 336 + base;
        float4 f0 = *(const float4*)p;
        float4 f1 = *(const float4*)(p + 4);
        val[0] = (short)f2bf(f0.x); val[1] = (short)f2bf(f0.y);
        val[2] = (short)f2bf(f0.z); val[3] = (short)f2bf(f0.w);
        val[4] = (short)f2bf(f1.x); val[5] = (short)f2bf(f1.y);
        val[6] = (short)f2bf(f1.z); val[7] = (short)f2bf(f1.w);
      }
      a = val;  // k>=336: A junk/zero x B zero-pad = 0
    } else {
      a = *(const bf16x8*)((const ushort_t*)Aptr + (size_t)arow_c * 128 + base);
    }
#pragma unroll
    for (int b = 0; b < 7; ++b) {
      bf16x8 bf = *(const bf16x8*)(wbase + (size_t)(b * 16 + m16) * Kp + base);
      acc[b] = __builtin_amdgcn_mfma_f32_16x16x32_bf16(a, bf, acc[b], 0, 0, 0);
    }
  }

  // epilogue: D[m=q*4+r][n]; node = n0 + w*16 + q*4 + r ; feat n = h*NBH + b*16 + m16
  int node_base = n0 + w * 16 + q * 4;
#pragma unroll
  for (int b = 0; b < 7; ++b) {
    int n = h * NBH + b * 16 + m16;
    float bv = (n >= 100 && n < 200) ? bias[n - 100] : 0.f;
#pragma unroll
    for (int r = 0; r < 4; ++r) {
      int node = node_base + r;
      if (node >= N_NODES) continue;
      float v = acc[b][r];
      if (n < 100) {
        Zrel[(size_t)node * 128 + n] = f2bf(v);
      } else if (n < 200) {
        Zroot[(size_t)node * 128 + (n - 100)] = f2bf(v + bv);
      }
    }
  }
}

// ---------------- gather: H[i] = relu(Zroot[i] + sum Zrel[src]) bf16, 128-col rows ----------
// R10: uint2 x 32 lanes covers a 256B row; wave = 2 edge slots (lanes 0-31 / 32-63)
// -> one global_load_dwordx2 instruction fetches TWO edge rows. shfl_xor(32) combines.
// Halves VMEM instruction count per edge vs R8; no idle lanes.

__global__ __launch_bounds__(256) void gather_bf16(
    const ushort_t* __restrict__ Zrel, const ushort_t* __restrict__ Zroot,
    const int* __restrict__ offs, const int* __restrict__ csr,
    ushort_t* __restrict__ H) {
  int node = blockIdx.x * 4 + (threadIdx.x >> 6);
  node = __builtin_amdgcn_readfirstlane(node);  // wave-uniform -> scalar offs loads
  int lane = threadIdx.x & 63;
  int half = lane >> 5;   // edge slot
  int sl = lane & 31;     // column group: cols sl*4 .. sl*4+3

  float a0[4], a1[4], a2[4], a3[4];
#pragma unroll
  for (int c = 0; c < 4; ++c) { a0[c] = 0.f; a1[c] = 0.f; a2[c] = 0.f; a3[c] = 0.f; }
  if (half == 0) {
    uint2 z = *(const uint2*)(Zroot + (size_t)node * 128 + sl * 4);
    a0[0] = bflo(z.x); a0[1] = bfhi(z.x); a0[2] = bflo(z.y); a0[3] = bfhi(z.y);
  }

  int s = offs[node], e = offs[node + 1];
  for (int j = s; j < e; j += 64) {
    int take = e - j; if (take > 64) take = 64;
    int vidx = (lane < take) ? csr[j + lane] : 0;  // coalesced index fetch
    int u = 0;
    for (; u + 8 <= take; u += 8) {  // 4 pairs = 8 edges, independent acc sets
      int idxp[4];
#pragma unroll
      for (int p = 0; p < 4; ++p) {
        int iA = __builtin_amdgcn_readlane(vidx, u + 2 * p);
        int iB = __builtin_amdgcn_readlane(vidx, u + 2 * p + 1);
        idxp[p] = half ? iB : iA;
      }
      uint2 v[4];
#pragma unroll
      for (int p = 0; p < 4; ++p)
        v[p] = *(const uint2*)(Zrel + (size_t)idxp[p] * 128 + sl * 4);
      a0[0] += bflo(v[0].x); a0[1] += bfhi(v[0].x); a0[2] += bflo(v[0].y); a0[3] += bfhi(v[0].y);
      a1[0] += bflo(v[1].x); a1[1] += bfhi(v[1].x); a1[2] += bflo(v[1].y); a1[3] += bfhi(v[1].y);
      a2[0] += bflo(v[2].x); a2[1] += bfhi(v[2].x); a2[2] += bflo(v[2].y); a2[3] += bfhi(v[2].y);
      a3[0] += bflo(v[3].x); a3[1] += bfhi(v[3].x); a3[2] += bflo(v[3].y); a3[3] += bfhi(v[3].y);
    }
    for (; u < take; u += 2) {  // masked tail pairs
      int iA = __builtin_amdgcn_readlane(vidx, u);
      int iB = (u + 1 < take) ? __builtin_amdgcn_readlane(vidx, u + 1) : iA;
      int idx = half ? iB : iA;
      uint2 v = *(const uint2*)(Zrel + (size_t)idx * 128 + sl * 4);
      if (u + half >= take) { v.x = 0u; v.y = 0u; }
      a0[0] += bflo(v.x); a0[1] += bfhi(v.x); a0[2] += bflo(v.y); a0[3] += bfhi(v.y);
    }
  }

#pragma unroll
  for (int c = 0; c < 4; ++c) {
    float t = (a0[c] + a1[c]) + (a2[c] + a3[c]);
    t += __shfl_xor(t, 32, 64);
    a0[c] = fmaxf(t, 0.f);
  }
  if (half == 0) {
    uint2 outp;
    outp.x = (uint_t)f2bf(a0[0]) | ((uint_t)f2bf(a0[1]) << 16);
    outp.y = (uint_t)f2bf(a0[2]) | ((uint_t)f2bf(a0[3]) << 16);
    *(uint2*)(H + (size_t)node * 128 + sl * 4) = outp;
  }
}

// ---------------- global mean pool: 1 block/graph, 16 node-rows x 64 lanes ----------------

__global__ __launch_bounds__(1024) void pool_kernel(const ushort_t* __restrict__ H,
                                                    const int* __restrict__ batch,
                                                    float* __restrict__ pooled) {
  int g = blockIdx.x;
  int t = threadIdx.x;
  int lo = 0, hi = N_NODES;
  while (lo < hi) { int mid = (lo + hi) >> 1; if (batch[mid] < g) lo = mid + 1; else hi = mid; }
  int s = lo;
  hi = N_NODES;
  while (lo < hi) { int mid = (lo + hi) >> 1; if (batch[mid] <= g) lo = mid + 1; else hi = mid; }
  int e = lo;

  int row = t >> 6;      // 16 node-rows
  int lane = t & 63;
  int off = (lane < 50 ? lane : 49) * 2;
  float a0 = 0.f, a1 = 0.f;
  for (int n = s + row; n < e; n += 16) {
    uint_t z = *(const uint_t*)(H + (size_t)n * 128 + off);
    a0 += bflo(z);
    a1 += bfhi(z);
  }
  __shared__ float sh[16][104];
  if (lane < 50) { sh[row][lane * 2] = a0; sh[row][lane * 2 + 1] = a1; }
  __syncthreads();
  if (t < 100) {
    float acc = 0.f;
#pragma unroll
    for (int r = 0; r < 16; ++r) acc += sh[r][t];
    int cnt = e - s;
    float d = (cnt > 0) ? (float)cnt : 1.f;
    pooled[(size_t)g * F + t] = acc / d;
  }
}

// ---------------- fused 3-layer MLP head (fp32) ----------------

__global__ void mlp_kernel(const float* __restrict__ pooled,
                           const float* __restrict__ lw1, const float* __restrict__ lb1,
                           const float* __restrict__ lw2, const float* __restrict__ lb2,
                           const float* __restrict__ lw3, const float* __restrict__ lb3,
                           float* __restrict__ out) {
  int g = blockIdx.x;
  int t = threadIdx.x;
  __shared__ float r0[F], r1[F], r2[F];
  if (t < F) r0[t] = pooled[(size_t)g * F + t];
  __syncthreads();
  if (t < F) {
    float s = lb1[t];
    for (int k = 0; k < F; ++k) s += r0[k] * lw1[t * F + k];
    r1[t] = fmaxf(s, 0.f);
  }
  __syncthreads();
  if (t < F) {
    float s = lb2[t];
    for (int k = 0; k < F; ++k) s += r1[k] * lw2[t * F + k];
    r2[t] = fmaxf(s, 0.f);
  }
  __syncthreads();
  if (t < 29) {
    float s = lb3[t];
    for (int k = 0; k < F; ++k) s += r2[k] * lw3[t * F + k];
    out[g * 29 + t] = s;
  }
}

// ---------------- launch ------------------------------------------------------------------------

extern "C" void kernel_launch(void* const* d_in, const int* in_sizes, int n_in,
                              void* d_out, int out_size, void* d_ws, size_t ws_size,
                              hipStream_t stream) {
  const float* x       = (const float*)d_in[0];
  const int*   ei      = (const int*)d_in[1];
  const int*   batch   = (const int*)d_in[2];
  const float* w1_rel  = (const float*)d_in[3];
  const float* w1_root = (const float*)d_in[4];
  const float* b1      = (const float*)d_in[5];
  const float* w_rel   = (const float*)d_in[6];
  const float* w_root  = (const float*)d_in[7];
  const float* bvec    = (const float*)d_in[8];
  const float* lw1     = (const float*)d_in[9];
  const float* lb1     = (const float*)d_in[10];
  const float* lw2     = (const float*)d_in[11];
  const float* lb2     = (const float*)d_in[12];
  const float* lw3     = (const float*)d_in[13];
  const float* lb3     = (const float*)d_in[14];
  float* out = (float*)d_out;

  // workspace layout
  char* ws = (char*)d_ws;
  size_t o = 0;
  auto alloc = [&](size_t bytes) { void* p = ws + o; o = (o + bytes + 511) & ~(size_t)511; return p; };
  ushort_t* H    = (ushort_t*)alloc((size_t)N_NODES * 128 * 2);   // 12.8 MB
  ushort_t* Zrel = (ushort_t*)alloc((size_t)N_NODES * 128 * 2);   // 12.8 MB (128-col padded)
  ushort_t* Zroot= (ushort_t*)alloc((size_t)N_NODES * 128 * 2);   // 12.8 MB
  ushort_t* Wp1  = (ushort_t*)alloc((size_t)224 * 352 * 2);
  ushort_t* Wp   = (ushort_t*)alloc((size_t)4 * 224 * 128 * 2);
  float*    pooled = (float*)alloc((size_t)N_GRAPHS * F * 4);
  int* cnt    = (int*)alloc((size_t)SCAN_PAD * 4);
  int* excl   = (int*)alloc((size_t)SCAN_PAD * 4);
  int* bsum   = (int*)alloc((size_t)128 * 4);
  int* offs   = (int*)alloc((size_t)(N_NODES + 1) * 4);
  int* cursor = (int*)alloc((size_t)(N_NODES + 1) * 4);
  int* csr    = (int*)alloc((size_t)N_EDGES * 4);

  const int E = N_EDGES;
  const int* srcv = ei;
  const int* dstv = ei + E;

  int nchunk = (E + FILL_CHUNK - 1) / FILL_CHUNK;  // 391
  // CSR build (parallel 3-phase scan; hist/fill dst-partitioned 8-way)
  hipMemsetAsync(cnt, 0, (size_t)SCAN_PAD * sizeof(int), stream);
  hist_kernel<<<nchunk * 8, 256, 0, stream>>>(dstv, cnt, E);
  scan1_kernel<<<SCAN_NB, SCAN_B, 0, stream>>>(cnt, excl, bsum);
  scan2_kernel<<<1, 128, 0, stream>>>(bsum);
  scan3_kernel<<<SCAN_NB, SCAN_B, 0, stream>>>(excl, bsum, offs, cursor);
  fill_kernel<<<nchunk * 8, 256, 0, stream>>>(srcv, dstv, cursor, csr, E);

  // weight packing (224 rows, zero-padded)
  pack_w1_kernel<<<224, 128, 0, stream>>>(w1_rel, w1_root, Wp1);
  pack_w_kernel<<<dim3(224, 4), 128, 0, stream>>>(w_rel, w_root, Wp);

  dim3 mmgrid((N_NODES + 63) / 64, 2);  // 782 x 2 feature-halves
  // layer 1: A = x fp32 [50000][336], Kp=352, NS=11 K-chunks
  conv_mfma<true, 11><<<mmgrid, 256, 0, stream>>>(x, Wp1, b1, Zrel, Zroot, 352);
  gather_bf16<<<N_NODES / 4, 256, 0, stream>>>(Zrel, Zroot, offs, csr, H);
  // layers 2..5: A = H bf16 [50000][128], Kp=128, NS=4
  for (int l = 0; l < 4; ++l) {
    conv_mfma<false, 4><<<mmgrid, 256, 0, stream>>>(H, Wp + (size_t)l * 224 * 128,
                                                    bvec + (size_t)l * F, Zrel, Zroot, 128);
    gather_bf16<<<N_NODES / 4, 256, 0, stream>>>(Zrel, Zroot, offs, csr, H);
  }
  pool_kernel<<<N_GRAPHS, 1024, 0, stream>>>(H, batch, pooled);
  mlp_kernel<<<N_GRAPHS, 128, 0, stream>>>(pooled, lw1, lb1, lw2, lb2, lw3, lb3, out);
}

// Round 11
// 500.384 us; speedup vs baseline: 1.1238x; 1.1238x over previous
//
#include <hip/hip_runtime.h>

#define N_NODES 50000
#define N_EDGES 800000
#define N_GRAPHS 256
#define F 100  // hidden dim

#define SCAN_B 512
#define SCAN_NB 98          // 98*512 = 50176 >= 50001
#define SCAN_PAD (SCAN_NB * SCAN_B)

#define PART_SZ 6250        // 8 dst partitions * 6250 = 50000
#define FILL_CHUNK 2048

#define NBH 112             // feature half-tile (224-row padded weights, 2 halves)

typedef __attribute__((ext_vector_type(8))) short bf16x8;
typedef __attribute__((ext_vector_type(4))) float f32x4;
typedef unsigned short ushort_t;
typedef unsigned int uint_t;

__device__ inline ushort_t f2bf(float f) {  // RNE float->bf16
  uint_t u = __float_as_uint(f);
  uint_t r = (u + 0x7fffu + ((u >> 16) & 1u)) >> 16;
  return (ushort_t)r;
}
__device__ inline float bflo(uint_t u) { return __uint_as_float(u << 16); }
__device__ inline float bfhi(uint_t u) { return __uint_as_float(u & 0xffff0000u); }

// ---------------- CSR build (counting sort by dst, rebuilt every call) ----------------
// hist/fill dst-range partitioned by blockIdx&7 (XCD round-robin heuristic) so csr/cursor
// atomics+scatters for a dst range stay in one XCD's L2 (R4->R6: fill 55 -> ~20 us).

__global__ __launch_bounds__(256) void hist_kernel(const int* __restrict__ dst,
                                                   int* __restrict__ cnt, int E) {
  int part = blockIdx.x & 7;
  int lo = part * PART_SZ, hi = lo + PART_SZ;
  int base = (blockIdx.x >> 3) * FILL_CHUNK;
  int end = base + FILL_CHUNK; if (end > E) end = E;
  for (int i = base + threadIdx.x; i < end; i += 256) {
    int d = dst[i];
    if (d >= lo && d < hi) atomicAdd(&cnt[d], 1);
  }
}

__global__ __launch_bounds__(SCAN_B) void scan1_kernel(const int* __restrict__ cnt,
                                                       int* __restrict__ excl,
                                                       int* __restrict__ bsum) {
  __shared__ int sh[SCAN_B];
  int t = threadIdx.x;
  int i = blockIdx.x * SCAN_B + t;
  int v = cnt[i];
  sh[t] = v;
  __syncthreads();
  for (int off = 1; off < SCAN_B; off <<= 1) {
    int u = (t >= off) ? sh[t - off] : 0;
    __syncthreads();
    sh[t] += u;
    __syncthreads();
  }
  excl[i] = sh[t] - v;
  if (t == SCAN_B - 1) bsum[blockIdx.x] = sh[t];
}

__global__ __launch_bounds__(128) void scan2_kernel(int* __restrict__ bsum) {
  __shared__ int sh[128];
  int t = threadIdx.x;
  int v = (t < SCAN_NB) ? bsum[t] : 0;
  sh[t] = v;
  __syncthreads();
  for (int off = 1; off < 128; off <<= 1) {
    int u = (t >= off) ? sh[t - off] : 0;
    __syncthreads();
    sh[t] += u;
    __syncthreads();
  }
  if (t < SCAN_NB) bsum[t] = sh[t] - v;
}

__global__ __launch_bounds__(SCAN_B) void scan3_kernel(const int* __restrict__ excl,
                                                       const int* __restrict__ bsum,
                                                       int* __restrict__ offs,
                                                       int* __restrict__ cursor) {
  int i = blockIdx.x * SCAN_B + threadIdx.x;
  int v = excl[i] + bsum[blockIdx.x];
  if (i <= N_NODES) { offs[i] = v; cursor[i] = v; }
}

__global__ __launch_bounds__(256) void fill_kernel(const int* __restrict__ src,
                                                   const int* __restrict__ dst,
                                                   int* __restrict__ cursor,
                                                   int* __restrict__ csr_src, int E) {
  int part = blockIdx.x & 7;
  int lo = part * PART_SZ, hi = lo + PART_SZ;
  int base = (blockIdx.x >> 3) * FILL_CHUNK;
  int end = base + FILL_CHUNK; if (end > E) end = E;
  for (int i = base + threadIdx.x; i < end; i += 256) {
    int d = dst[i];
    if (d >= lo && d < hi) {
      int p = atomicAdd(&cursor[d], 1);
      csr_src[p] = src[i];
    }
  }
}

// ---------------- weight packing: [224][Kp] bf16, zero-padded (rows 200..223, k>=K zero) -------

__global__ void pack_w1_kernel(const float* __restrict__ w1_rel, const float* __restrict__ w1_root,
                               ushort_t* __restrict__ Wp1) {
  int row = blockIdx.x;  // 224
  for (int k = threadIdx.x; k < 352; k += 128) {
    float v = 0.f;
    if (k < 336) {
      if (row < 100) v = w1_rel[row * 336 + k];
      else if (row < 200) v = w1_root[(row - 100) * 336 + k];
    }
    Wp1[(size_t)row * 352 + k] = f2bf(v);
  }
}

__global__ void pack_w_kernel(const float* __restrict__ w_rel, const float* __restrict__ w_root,
                              ushort_t* __restrict__ Wp) {
  int row = blockIdx.x;  // 224
  int l = blockIdx.y;    // 4
  int k = threadIdx.x;   // 128
  float v = 0.f;
  if (k < 100) {
    if (row < 100) v = w_rel[((size_t)l * 100 + row) * 100 + k];
    else if (row < 200) v = w_root[((size_t)l * 100 + row - 100) * 100 + k];
  }
  Wp[((size_t)l * 224 + row) * 128 + k] = f2bf(v);
}

// ---------------- MFMA conv: Zrel = A@Wrel.T (bf16), Zroot = A@Wroot.T + b ----------------
// R11 synthesis of R6-R10 evidence:
//  (a) B fetched ONCE per block into LDS (R10 showed per-wave B re-fetch from L2 = +60%),
//  (b) A-fragments loaded DIRECT from global (wave-private rows; 16B/lane coalesced;
//      R6-R9 showed the A global->LDS->reg staging pipeline was pure overhead),
//  (c) exactly ONE barrier (after B staging); K-loop is barrier-free so the compiler
//      pipelines A loads across chunks with fine-grained vmcnt (no barrier drain).
// LDS rows padded +8 shorts -> fragment ds_read_b128 is 2-way bank aliased only (free).
// Layer 1 half: 80.6 KB LDS (2 blocks/CU); layers 2-5: 30.5 KB (5 blocks/CU).
// Zrel/Zroot 128-col padded; pad cols never written (poison annihilated by relu +
// zero weight-pad columns downstream).

template <bool AF32, int NS, int KP>
__global__ __launch_bounds__(256) void conv_mfma(
    const void* __restrict__ Aptr, const ushort_t* __restrict__ Wp,
    const float* __restrict__ bias,
    ushort_t* __restrict__ Zrel, ushort_t* __restrict__ Zroot) {
  constexpr int SROWL = KP + 8;
  __shared__ short blds[NBH * SROWL];

  int tid = threadIdx.x;
  int w = tid >> 6, lane = tid & 63, q = lane >> 4, m16 = lane & 15;
  int n0 = blockIdx.x * 64;
  int h = blockIdx.y;  // feature half: weight rows [h*NBH, h*NBH+NBH)
  int arow = n0 + w * 16 + m16;
  int arow_c = arow < N_NODES ? arow : N_NODES - 1;  // clamp load address only

  // ---- stage B half into LDS once (16B chunks) ----
  {
    const ushort_t* wsrc = Wp + (size_t)(h * NBH) * KP;
    constexpr int NCH = NBH * (KP / 8);  // 16B chunks
    for (int c = tid; c < NCH; c += 256) {
      int r = c / (KP / 8), qq = c % (KP / 8);
      *(bf16x8*)&blds[r * SROWL + qq * 8] = *(const bf16x8*)(wsrc + (size_t)r * KP + qq * 8);
    }
  }
  __syncthreads();  // the only barrier

  f32x4 acc[7];
#pragma unroll
  for (int b = 0; b < 7; ++b) acc[b] = (f32x4)0.f;

#pragma unroll
  for (int s = 0; s < NS; ++s) {
    int base = s * 32 + q * 8;
    bf16x8 a;
    if (AF32) {
      bf16x8 val = (bf16x8)0;
      if (base < 336) {  // 336 % 8 == 0: no straddle
        const float* p = (const float*)Aptr + (size_t)arow_c * 336 + base;
        float4 f0 = *(const float4*)p;
        float4 f1 = *(const float4*)(p + 4);
        val[0] = (short)f2bf(f0.x); val[1] = (short)f2bf(f0.y);
        val[2] = (short)f2bf(f0.z); val[3] = (short)f2bf(f0.w);
        val[4] = (short)f2bf(f1.x); val[5] = (short)f2bf(f1.y);
        val[6] = (short)f2bf(f1.z); val[7] = (short)f2bf(f1.w);
      }
      a = val;  // k>=336: A zero x B zero-pad
    } else {
      a = *(const bf16x8*)((const ushort_t*)Aptr + (size_t)arow_c * 128 + base);
    }
#pragma unroll
    for (int b = 0; b < 7; ++b) {
      bf16x8 bf = *(const bf16x8*)&blds[(b * 16 + m16) * SROWL + base];
      acc[b] = __builtin_amdgcn_mfma_f32_16x16x32_bf16(a, bf, acc[b], 0, 0, 0);
    }
  }

  // epilogue: D[m=q*4+r][n]; node = n0 + w*16 + q*4 + r ; feat n = h*NBH + b*16 + m16
  int node_base = n0 + w * 16 + q * 4;
#pragma unroll
  for (int b = 0; b < 7; ++b) {
    int n = h * NBH + b * 16 + m16;
    float bv = (n >= 100 && n < 200) ? bias[n - 100] : 0.f;
#pragma unroll
    for (int r = 0; r < 4; ++r) {
      int node = node_base + r;
      if (node >= N_NODES) continue;
      float v = acc[b][r];
      if (n < 100) {
        Zrel[(size_t)node * 128 + n] = f2bf(v);
      } else if (n < 200) {
        Zroot[(size_t)node * 128 + (n - 100)] = f2bf(v + bv);
      }
    }
  }
}

// ---------------- gather: H[i] = relu(Zroot[i] + sum Zrel[src]) bf16, 128-col rows ----------
// uint2 x 32 lanes covers a 256B row; wave = 2 edge slots (lanes 0-31 / 32-63)
// -> one global_load_dwordx2 fetches TWO edge rows. shfl_xor(32) combines.

__global__ __launch_bounds__(256) void gather_bf16(
    const ushort_t* __restrict__ Zrel, const ushort_t* __restrict__ Zroot,
    const int* __restrict__ offs, const int* __restrict__ csr,
    ushort_t* __restrict__ H) {
  int node = blockIdx.x * 4 + (threadIdx.x >> 6);
  node = __builtin_amdgcn_readfirstlane(node);  // wave-uniform -> scalar offs loads
  int lane = threadIdx.x & 63;
  int half = lane >> 5;   // edge slot
  int sl = lane & 31;     // column group: cols sl*4 .. sl*4+3

  float a0[4], a1[4], a2[4], a3[4];
#pragma unroll
  for (int c = 0; c < 4; ++c) { a0[c] = 0.f; a1[c] = 0.f; a2[c] = 0.f; a3[c] = 0.f; }
  if (half == 0) {
    uint2 z = *(const uint2*)(Zroot + (size_t)node * 128 + sl * 4);
    a0[0] = bflo(z.x); a0[1] = bfhi(z.x); a0[2] = bflo(z.y); a0[3] = bfhi(z.y);
  }

  int s = offs[node], e = offs[node + 1];
  for (int j = s; j < e; j += 64) {
    int take = e - j; if (take > 64) take = 64;
    int vidx = (lane < take) ? csr[j + lane] : 0;  // coalesced index fetch
    int u = 0;
    for (; u + 8 <= take; u += 8) {  // 4 pairs = 8 edges, independent acc sets
      int idxp[4];
#pragma unroll
      for (int p = 0; p < 4; ++p) {
        int iA = __builtin_amdgcn_readlane(vidx, u + 2 * p);
        int iB = __builtin_amdgcn_readlane(vidx, u + 2 * p + 1);
        idxp[p] = half ? iB : iA;
      }
      uint2 v[4];
#pragma unroll
      for (int p = 0; p < 4; ++p)
        v[p] = *(const uint2*)(Zrel + (size_t)idxp[p] * 128 + sl * 4);
      a0[0] += bflo(v[0].x); a0[1] += bfhi(v[0].x); a0[2] += bflo(v[0].y); a0[3] += bfhi(v[0].y);
      a1[0] += bflo(v[1].x); a1[1] += bfhi(v[1].x); a1[2] += bflo(v[1].y); a1[3] += bfhi(v[1].y);
      a2[0] += bflo(v[2].x); a2[1] += bfhi(v[2].x); a2[2] += bflo(v[2].y); a2[3] += bfhi(v[2].y);
      a3[0] += bflo(v[3].x); a3[1] += bfhi(v[3].x); a3[2] += bflo(v[3].y); a3[3] += bfhi(v[3].y);
    }
    for (; u < take; u += 2) {  // masked tail pairs
      int iA = __builtin_amdgcn_readlane(vidx, u);
      int iB = (u + 1 < take) ? __builtin_amdgcn_readlane(vidx, u + 1) : iA;
      int idx = half ? iB : iA;
      uint2 v = *(const uint2*)(Zrel + (size_t)idx * 128 + sl * 4);
      if (u + half >= take) { v.x = 0u; v.y = 0u; }
      a0[0] += bflo(v.x); a0[1] += bfhi(v.x); a0[2] += bflo(v.y); a0[3] += bfhi(v.y);
    }
  }

#pragma unroll
  for (int c = 0; c < 4; ++c) {
    float t = (a0[c] + a1[c]) + (a2[c] + a3[c]);
    t += __shfl_xor(t, 32, 64);
    a0[c] = fmaxf(t, 0.f);
  }
  if (half == 0) {
    uint2 outp;
    outp.x = (uint_t)f2bf(a0[0]) | ((uint_t)f2bf(a0[1]) << 16);
    outp.y = (uint_t)f2bf(a0[2]) | ((uint_t)f2bf(a0[3]) << 16);
    *(uint2*)(H + (size_t)node * 128 + sl * 4) = outp;
  }
}

// ---------------- global mean pool: 1 block/graph, 16 node-rows x 64 lanes ----------------

__global__ __launch_bounds__(1024) void pool_kernel(const ushort_t* __restrict__ H,
                                                    const int* __restrict__ batch,
                                                    float* __restrict__ pooled) {
  int g = blockIdx.x;
  int t = threadIdx.x;
  int lo = 0, hi = N_NODES;
  while (lo < hi) { int mid = (lo + hi) >> 1; if (batch[mid] < g) lo = mid + 1; else hi = mid; }
  int s = lo;
  hi = N_NODES;
  while (lo < hi) { int mid = (lo + hi) >> 1; if (batch[mid] <= g) lo = mid + 1; else hi = mid; }
  int e = lo;

  int row = t >> 6;      // 16 node-rows
  int lane = t & 63;
  int off = (lane < 50 ? lane : 49) * 2;
  float a0 = 0.f, a1 = 0.f;
  for (int n = s + row; n < e; n += 16) {
    uint_t z = *(const uint_t*)(H + (size_t)n * 128 + off);
    a0 += bflo(z);
    a1 += bfhi(z);
  }
  __shared__ float sh[16][104];
  if (lane < 50) { sh[row][lane * 2] = a0; sh[row][lane * 2 + 1] = a1; }
  __syncthreads();
  if (t < 100) {
    float acc = 0.f;
#pragma unroll
    for (int r = 0; r < 16; ++r) acc += sh[r][t];
    int cnt = e - s;
    float d = (cnt > 0) ? (float)cnt : 1.f;
    pooled[(size_t)g * F + t] = acc / d;
  }
}

// ---------------- fused 3-layer MLP head (fp32) ----------------

__global__ void mlp_kernel(const float* __restrict__ pooled,
                           const float* __restrict__ lw1, const float* __restrict__ lb1,
                           const float* __restrict__ lw2, const float* __restrict__ lb2,
                           const float* __restrict__ lw3, const float* __restrict__ lb3,
                           float* __restrict__ out) {
  int g = blockIdx.x;
  int t = threadIdx.x;
  __shared__ float r0[F], r1[F], r2[F];
  if (t < F) r0[t] = pooled[(size_t)g * F + t];
  __syncthreads();
  if (t < F) {
    float s = lb1[t];
    for (int k = 0; k < F; ++k) s += r0[k] * lw1[t * F + k];
    r1[t] = fmaxf(s, 0.f);
  }
  __syncthreads();
  if (t < F) {
    float s = lb2[t];
    for (int k = 0; k < F; ++k) s += r1[k] * lw2[t * F + k];
    r2[t] = fmaxf(s, 0.f);
  }
  __syncthreads();
  if (t < 29) {
    float s = lb3[t];
    for (int k = 0; k < F; ++k) s += r2[k] * lw3[t * F + k];
    out[g * 29 + t] = s;
  }
}

// ---------------- launch ------------------------------------------------------------------------

extern "C" void kernel_launch(void* const* d_in, const int* in_sizes, int n_in,
                              void* d_out, int out_size, void* d_ws, size_t ws_size,
                              hipStream_t stream) {
  const float* x       = (const float*)d_in[0];
  const int*   ei      = (const int*)d_in[1];
  const int*   batch   = (const int*)d_in[2];
  const float* w1_rel  = (const float*)d_in[3];
  const float* w1_root = (const float*)d_in[4];
  const float* b1      = (const float*)d_in[5];
  const float* w_rel   = (const float*)d_in[6];
  const float* w_root  = (const float*)d_in[7];
  const float* bvec    = (const float*)d_in[8];
  const float* lw1     = (const float*)d_in[9];
  const float* lb1     = (const float*)d_in[10];
  const float* lw2     = (const float*)d_in[11];
  const float* lb2     = (const float*)d_in[12];
  const float* lw3     = (const float*)d_in[13];
  const float* lb3     = (const float*)d_in[14];
  float* out = (float*)d_out;

  // workspace layout
  char* ws = (char*)d_ws;
  size_t o = 0;
  auto alloc = [&](size_t bytes) { void* p = ws + o; o = (o + bytes + 511) & ~(size_t)511; return p; };
  ushort_t* H    = (ushort_t*)alloc((size_t)N_NODES * 128 * 2);   // 12.8 MB
  ushort_t* Zrel = (ushort_t*)alloc((size_t)N_NODES * 128 * 2);   // 12.8 MB (128-col padded)
  ushort_t* Zroot= (ushort_t*)alloc((size_t)N_NODES * 128 * 2);   // 12.8 MB
  ushort_t* Wp1  = (ushort_t*)alloc((size_t)224 * 352 * 2);
  ushort_t* Wp   = (ushort_t*)alloc((size_t)4 * 224 * 128 * 2);
  float*    pooled = (float*)alloc((size_t)N_GRAPHS * F * 4);
  int* cnt    = (int*)alloc((size_t)SCAN_PAD * 4);
  int* excl   = (int*)alloc((size_t)SCAN_PAD * 4);
  int* bsum   = (int*)alloc((size_t)128 * 4);
  int* offs   = (int*)alloc((size_t)(N_NODES + 1) * 4);
  int* cursor = (int*)alloc((size_t)(N_NODES + 1) * 4);
  int* csr    = (int*)alloc((size_t)N_EDGES * 4);

  const int E = N_EDGES;
  const int* srcv = ei;
  const int* dstv = ei + E;

  int nchunk = (E + FILL_CHUNK - 1) / FILL_CHUNK;  // 391
  // CSR build (parallel 3-phase scan; hist/fill dst-partitioned 8-way)
  hipMemsetAsync(cnt, 0, (size_t)SCAN_PAD * sizeof(int), stream);
  hist_kernel<<<nchunk * 8, 256, 0, stream>>>(dstv, cnt, E);
  scan1_kernel<<<SCAN_NB, SCAN_B, 0, stream>>>(cnt, excl, bsum);
  scan2_kernel<<<1, 128, 0, stream>>>(bsum);
  scan3_kernel<<<SCAN_NB, SCAN_B, 0, stream>>>(excl, bsum, offs, cursor);
  fill_kernel<<<nchunk * 8, 256, 0, stream>>>(srcv, dstv, cursor, csr, E);

  // weight packing (224 rows, zero-padded)
  pack_w1_kernel<<<224, 128, 0, stream>>>(w1_rel, w1_root, Wp1);
  pack_w_kernel<<<dim3(224, 4), 128, 0, stream>>>(w_rel, w_root, Wp);

  dim3 mmgrid((N_NODES + 63) / 64, 2);  // 782 x 2 feature-halves
  // layer 1: A = x fp32 [50000][336], Kp=352, NS=11
  conv_mfma<true, 11, 352><<<mmgrid, 256, 0, stream>>>(x, Wp1, b1, Zrel, Zroot);
  gather_bf16<<<N_NODES / 4, 256, 0, stream>>>(Zrel, Zroot, offs, csr, H);
  // layers 2..5: A = H bf16 [50000][128], Kp=128, NS=4
  for (int l = 0; l < 4; ++l) {
    conv_mfma<false, 4, 128><<<mmgrid, 256, 0, stream>>>(H, Wp + (size_t)l * 224 * 128,
                                                         bvec + (size_t)l * F, Zrel, Zroot);
    gather_bf16<<<N_NODES / 4, 256, 0, stream>>>(Zrel, Zroot, offs, csr, H);
  }
  pool_kernel<<<N_GRAPHS, 1024, 0, stream>>>(H, batch, pooled);
  mlp_kernel<<<N_GRAPHS, 128, 0, stream>>>(pooled, lw1, lb1, lw2, lb2, lw3, lb3, out);
}